// Round 7
// baseline (489.918 us; speedup 1.0000x reference)
//
#include <hip/hip_runtime.h>
#include <hip/hip_bf16.h>

// SparK densify: channels-first LayerNorm + mask-token fill + 1x1 conv (128->128).
// B=32, C=128, H=W=128, D=128. fp32 in/out; mask = int32 bools (probe-guarded).
//
// R6: LN folded into conv epilogue (conv is linear):
//   active:   out_d = rs*(G x)_d - rs*mu*g1_d + c0_d     G = w*gamma (bf16)
//   inactive: out_d = cm_d                               g1 = G.1 (bf16-consistent)
//   => out = rsa*acc + t1*g1_d + a*dd_d + cm_d,  rsa=a*rs, t1=-a*rs*mu, dd=c0-cm
// MFMA runs on raw bf16(x); stats+pack in one pass; TWO barriers total.
// Tile: 256 thr / 64 positions; wave owns 32 d; LDS ~19KB; launch_bounds(256,4).

#define CC   128
#define DD   128
#define HWW  16384
#define PP   64
#define TPB  256

typedef __attribute__((ext_vector_type(8))) short short8;
typedef __attribute__((ext_vector_type(4))) float f32x4;

__device__ __forceinline__ float b2f(unsigned short u) {
    return __uint_as_float(((unsigned int)u) << 16);
}
__device__ __forceinline__ unsigned short f2b(float f) {   // RNE fp32->bf16
    unsigned int u = __float_as_uint(f);
    return (unsigned short)((u + 0x7FFFu + ((u >> 16) & 1u)) >> 16);
}
__device__ __forceinline__ unsigned int pk2(float lo, float hi) {
    return (unsigned int)f2b(lo) | ((unsigned int)f2b(hi) << 16);
}
__device__ __forceinline__ float ldf(const void* p, int i, bool bf) {
    return bf ? b2f(((const unsigned short*)p)[i]) : ((const float*)p)[i];
}

// wpack[((g*4+kk)*64+lane)*8+j] = bf16(w[d,c]*gamma[c]), d=g*16+(lane&15),
// c = kk*32 + ((lane>>4)&3)*8 + j   (B-fragment order for mfma_f32_16x16x32_bf16)
__global__ void prep_pack_w(const void* __restrict__ w, const void* __restrict__ gamma,
                            unsigned short* __restrict__ wpack) {
    const bool bf = (((const unsigned int*)gamma)[0] == 0x3F803F80u);
    int e = blockIdx.x * blockDim.x + threadIdx.x;   // 0..16383
    int j = e & 7, lane = (e >> 3) & 63, kk = (e >> 9) & 3, g = e >> 11;
    int d = g * 16 + (lane & 15);
    int c = kk * 32 + ((lane >> 4) & 3) * 8 + j;
    wpack[e] = f2b(ldf(w, d * CC + c, bf) * ldf(gamma, c, bf));
}

// per-d constants: g1 = sum_c bf16(w*gamma) (consistent with MFMA operand),
// cm = sum_c w*mt + bias, dd = sum_c w*(beta-mt)
__global__ void prep_vec(const void* __restrict__ w, const void* __restrict__ gamma,
                         const void* __restrict__ beta, const void* __restrict__ mtok,
                         const void* __restrict__ bias, float* __restrict__ g1b,
                         float* __restrict__ cmb, float* __restrict__ ddb) {
    const bool bf = (((const unsigned int*)gamma)[0] == 0x3F803F80u);
    const int d = threadIdx.x;
    float g1 = 0.f, cm = 0.f, dd = 0.f;
    for (int c = 0; c < CC; ++c) {
        const float wv = ldf(w, d * CC + c, bf);
        g1 += b2f(f2b(wv * ldf(gamma, c, bf)));
        cm = fmaf(wv, ldf(mtok, c, bf), cm);
        dd = fmaf(wv, ldf(beta, c, bf) - ldf(mtok, c, bf), dd);
    }
    g1b[d] = g1;
    cmb[d] = cm + ldf(bias, d, bf);
    ddb[d] = dd;
}

__global__ __launch_bounds__(TPB, 4)
void spark_densify_v6(const void* __restrict__ x,    // (B,C,H,W) fp32 (probe-guarded)
                      const void* __restrict__ act,  // (B,1,H,W) bool (i32 or u8)
                      const void* __restrict__ gam,  // probe only
                      const unsigned short* __restrict__ wpack,
                      const float* __restrict__ g1b,
                      const float* __restrict__ cmb,
                      const float* __restrict__ ddb,
                      float* __restrict__ out)       // (B,D,H,W) fp32
{
    __shared__ __align__(16) uint4 afrag[16 * 64];   // 16KB: (pt*4+kk)*64 + slot^pt
    __shared__ __align__(16) float ps_s[4][PP];      // 1KB
    __shared__ __align__(16) float ps_q[4][PP];      // 1KB
    __shared__ __align__(16) float st_rsa[PP];
    __shared__ __align__(16) float st_t1[PP];
    __shared__ __align__(16) float st_a[PP];

    const int t    = threadIdx.x;
    const int wv   = t >> 6;
    const int lane = t & 63;
    const int bk   = blockIdx.x;          // 0..8191
    const int b    = bk >> 8;
    const int pos0 = (bk & 255) * PP;

    // ---- runtime dtype probes (uniform) ----
    const bool bf = (((const unsigned int*)gam)[0] == 0x3F803F80u);
    bool mint = true;
    #pragma unroll
    for (int i = 0; i < 16; ++i) mint = mint && (((const unsigned int*)act)[i] <= 1u);

    // ---- B-fragments early (L2-resident, hide latency) ----
    short8 bw[2][4];
    #pragma unroll
    for (int dt = 0; dt < 2; ++dt)
        #pragma unroll
        for (int kk = 0; kk < 4; ++kk)
            bw[dt][kk] = *(const short8*)(wpack + (((wv * 2 + dt) * 4 + kk) * 64 + lane) * 8);

    // ---------- phase 1: load x, partial stats, pack A-frags ----------
    const int pq = t & 15;                // position-quad (p = pq*4..+3)
    const int cg = t >> 4;                // channel-group (c = cg*8..+7)
    const long xbase = (long)b * CC * HWW + pos0 + pq * 4;

    float4 v[8];
    float s0=0.f,s1=0.f,s2=0.f,s3=0.f;
    float q0=0.f,q1=0.f,q2=0.f,q3=0.f;
    if (!bf) {
        const float* xf = (const float*)x;
        #pragma unroll
        for (int i = 0; i < 8; ++i) {
            v[i] = *(const float4*)(xf + xbase + (long)(cg * 8 + i) * HWW);
            s0 += v[i].x; q0 = fmaf(v[i].x, v[i].x, q0);
            s1 += v[i].y; q1 = fmaf(v[i].y, v[i].y, q1);
            s2 += v[i].z; q2 = fmaf(v[i].z, v[i].z, q2);
            s3 += v[i].w; q3 = fmaf(v[i].w, v[i].w, q3);
        }
    } else {
        const unsigned short* xh = (const unsigned short*)x;
        #pragma unroll
        for (int i = 0; i < 8; ++i) {
            const ushort4 u = *(const ushort4*)(xh + xbase + (long)(cg * 8 + i) * HWW);
            v[i] = make_float4(b2f(u.x), b2f(u.y), b2f(u.z), b2f(u.w));
            s0 += v[i].x; q0 = fmaf(v[i].x, v[i].x, q0);
            s1 += v[i].y; q1 = fmaf(v[i].y, v[i].y, q1);
            s2 += v[i].z; q2 = fmaf(v[i].z, v[i].z, q2);
            s3 += v[i].w; q3 = fmaf(v[i].w, v[i].w, q3);
        }
    }
    // combine 4 same-pq lanes (cg = wv*4 + {0..3}) -> wave partial over 32 c
    s0 += __shfl_xor(s0, 16); q0 += __shfl_xor(q0, 16);
    s1 += __shfl_xor(s1, 16); q1 += __shfl_xor(q1, 16);
    s2 += __shfl_xor(s2, 16); q2 += __shfl_xor(q2, 16);
    s3 += __shfl_xor(s3, 16); q3 += __shfl_xor(q3, 16);
    s0 += __shfl_xor(s0, 32); q0 += __shfl_xor(q0, 32);
    s1 += __shfl_xor(s1, 32); q1 += __shfl_xor(q1, 32);
    s2 += __shfl_xor(s2, 32); q2 += __shfl_xor(q2, 32);
    s3 += __shfl_xor(s3, 32); q3 += __shfl_xor(q3, 32);
    if (lane < 16) {
        *(float4*)&ps_s[wv][lane * 4] = make_float4(s0, s1, s2, s3);
        *(float4*)&ps_q[wv][lane * 4] = make_float4(q0, q1, q2, q3);
    }

    // pack A-frags from RAW x (bf16). A-frag (pt,kk): lane L elem j =
    // x[c=kk*32+(L>>4)*8+j][p=pt*16+(L&15)]; stored at slot^pt (bank swizzle).
    {
        const int kk = cg >> 2;           // == wv within a wave
        const int sb = 16 * (cg & 3);
        #pragma unroll
        for (int k = 0; k < 4; ++k) {
            const int pt   = pq >> 2;
            const int slot = (pq & 3) * 4 + k + sb;
            const int idx  = (pt * 4 + kk) * 64 + (slot ^ pt);
            uint4 wq;
            if      (k == 0) wq = make_uint4(pk2(v[0].x,v[1].x), pk2(v[2].x,v[3].x),
                                             pk2(v[4].x,v[5].x), pk2(v[6].x,v[7].x));
            else if (k == 1) wq = make_uint4(pk2(v[0].y,v[1].y), pk2(v[2].y,v[3].y),
                                             pk2(v[4].y,v[5].y), pk2(v[6].y,v[7].y));
            else if (k == 2) wq = make_uint4(pk2(v[0].z,v[1].z), pk2(v[2].z,v[3].z),
                                             pk2(v[4].z,v[5].z), pk2(v[6].z,v[5].z));
            else             wq = make_uint4(pk2(v[0].w,v[1].w), pk2(v[2].w,v[3].w),
                                             pk2(v[4].w,v[5].w), pk2(v[6].w,v[7].w));
            if (k == 2) wq = make_uint4(pk2(v[0].z,v[1].z), pk2(v[2].z,v[3].z),
                                        pk2(v[4].z,v[5].z), pk2(v[6].z,v[7].z));
            afrag[idx] = wq;
        }
    }
    __syncthreads();   // barrier 1: afrag + ps ready

    // ---------- phase 2: finalize stats (wave 0) ----------
    if (t < PP) {
        float ss = ps_s[0][t] + ps_s[1][t] + ps_s[2][t] + ps_s[3][t];
        float qq = ps_q[0][t] + ps_q[1][t] + ps_q[2][t] + ps_q[3][t];
        const float mu  = ss * (1.0f / 128.0f);
        const float var = qq * (1.0f / 128.0f) - mu * mu;
        const float rs  = rsqrtf(var + 1e-6f);
        const long  ap  = (long)b * HWW + pos0 + t;
        const bool  a   = mint ? (((const int*)act)[ap] != 0)
                               : (((const unsigned char*)act)[ap] != 0);
        const float af  = a ? 1.f : 0.f;
        st_rsa[t] = af * rs;
        st_t1[t]  = -af * rs * mu;
        st_a[t]   = af;
    }

    // ---------- phase 3: MFMA on raw x-frags ----------
    f32x4 acc[2][4];
    #pragma unroll
    for (int dt = 0; dt < 2; ++dt)
        #pragma unroll
        for (int pt = 0; pt < 4; ++pt) acc[dt][pt] = (f32x4){0.f, 0.f, 0.f, 0.f};

    #pragma unroll
    for (int pt = 0; pt < 4; ++pt) {
        short8 af_[4];
        #pragma unroll
        for (int kk = 0; kk < 4; ++kk)
            af_[kk] = *(const short8*)&afrag[(pt * 4 + kk) * 64 + (lane ^ pt)];
        #pragma unroll
        for (int dt = 0; dt < 2; ++dt)
            #pragma unroll
            for (int kk = 0; kk < 4; ++kk)
                acc[dt][pt] = __builtin_amdgcn_mfma_f32_16x16x32_bf16(
                                  af_[kk], bw[dt][kk], acc[dt][pt], 0, 0, 0);
    }
    __syncthreads();   // barrier 2: st arrays ready

    // ---------- epilogue: affine LN+mask correction, fp32 stores ----------
    // C-layout: col(d)=lane&15, row(p)=pt*16+(lane>>4)*4+r
    const int rg = (lane >> 4) * 4;
    #pragma unroll
    for (int pt = 0; pt < 4; ++pt) {
        const int p0 = pt * 16 + rg;
        const float4 rsa = *(const float4*)&st_rsa[p0];
        const float4 t1  = *(const float4*)&st_t1[p0];
        const float4 av  = *(const float4*)&st_a[p0];
        #pragma unroll
        for (int dt = 0; dt < 2; ++dt) {
            const int dch = wv * 32 + dt * 16 + (lane & 15);
            const float g1 = g1b[dch], cm = cmb[dch], dd = ddb[dch];
            float4 o;
            o.x = fmaf(rsa.x, acc[dt][pt][0], fmaf(t1.x, g1, fmaf(av.x, dd, cm)));
            o.y = fmaf(rsa.y, acc[dt][pt][1], fmaf(t1.y, g1, fmaf(av.y, dd, cm)));
            o.z = fmaf(rsa.z, acc[dt][pt][2], fmaf(t1.z, g1, fmaf(av.z, dd, cm)));
            o.w = fmaf(rsa.w, acc[dt][pt][3], fmaf(t1.w, g1, fmaf(av.w, dd, cm)));
            *(float4*)(out + (long)b * DD * HWW + (long)dch * HWW + pos0 + p0) = o;
        }
    }
}

extern "C" void kernel_launch(void* const* d_in, const int* in_sizes, int n_in,
                              void* d_out, int out_size, void* d_ws, size_t ws_size,
                              hipStream_t stream) {
    const void* x     = d_in[0];
    const void* act   = d_in[1];
    const void* gamma = d_in[2];
    const void* beta  = d_in[3];
    const void* mtok  = d_in[4];
    const void* convw = d_in[5];
    const void* bias  = d_in[6];
    float* out = (float*)d_out;

    unsigned short* wpack = (unsigned short*)d_ws;            // 32KB
    float* g1b = (float*)((char*)d_ws + 32768);               // 512B
    float* cmb = g1b + DD;                                    // 512B
    float* ddb = cmb + DD;                                    // 512B

    prep_pack_w<<<64, 256, 0, stream>>>(convw, gamma, wpack);
    prep_vec<<<1, DD, 0, stream>>>(convw, gamma, beta, mtok, bias, g1b, cmb, ddb);

    const int nblocks = (32 * HWW) / PP;   // 8192
    spark_densify_v6<<<nblocks, TPB, 0, stream>>>(
        x, act, gamma, wpack, g1b, cmb, ddb, out);
}